// Round 9
// baseline (897.609 us; speedup 1.0000x reference)
//
#include <hip/hip_runtime.h>
#include <hip/hip_bf16.h>

typedef unsigned short u16;
typedef __bf16 bf16x8 __attribute__((ext_vector_type(8)));
typedef float f32x16 __attribute__((ext_vector_type(16)));

#define DEVI __device__ __forceinline__

DEVI u16 f2bf(float f) {
    unsigned u = __builtin_bit_cast(unsigned, f);
    u += 0x7fff + ((u >> 16) & 1);   // RNE; inputs are finite
    return (u16)(u >> 16);
}
DEVI float bf2f(u16 h) {
    unsigned u = ((unsigned)h) << 16;
    return __builtin_bit_cast(float, u);
}

typedef __attribute__((address_space(1))) const unsigned GU32;
typedef __attribute__((address_space(3))) unsigned LU32;

DEVI void gload_lds16(const void* g, void* l) {
    __builtin_amdgcn_global_load_lds((GU32*)g, (LU32*)l, 16, 0, 0);
}

// Bijective XCD-chunk swizzle (m204).
DEVI int xcd_swz(int orig, int n) {
    int q = n >> 3, r = n & 7, x = orig & 7, o = orig >> 3;
    return (x < r ? x * (q + 1) : r * (q + 1) + (x - r) * q) + o;
}

// ===========================================================================
// 128x256 GEMM core on mfma_f32_32x32x16_bf16, ring-3 BK=32 slots, 72 KiB.
//   C[128x256] += A[MxK] * B^T  (B stored N x K row-major)
//   512 thr = 8 waves (2M x 4N); wave tile 64x64 = 2x2 frags of 32x32.
//   LDS slot (24 KB): A [kc=4][row=128][16B] + B [kc=4][row=256][16B] at
//   +8192 B. k-major chunk layout -> ds_read_b128 is lane-contiguous
//   (conflict-free, NO swizzle) and global_load_lds staging is plain linear.
//   Fragment mapping (16x16 pattern scaled, m74/m101 C/D):
//     A/B: row/col = lane&31, k = (lane>>5)*8 + e  (per 16-k subk)
//     C/D: col = lane&31, row = (reg&3) + 8*(reg>>2) + 4*(lane>>5)
//   Schedule identical to R8 (passing): per iter i {ds_read slot i%3;
//   stage slot (i+2)%3; 8 MFMA (2 subk x 2x2), setprio; vmcnt(3) drains
//   slot i+1 (own loads), s_barrier; sched_barrier}.
// ===========================================================================
DEVI void gemm_core(const u16* __restrict__ A, int lda,
                    const u16* __restrict__ B, int ldb,
                    int NK, int m0, int n0, u16* lds, f32x16 (&acc)[2][2])
{
    const int tid = threadIdx.x;
    const int wave = tid >> 6, lane = tid & 63;
    const int l31 = lane & 31, lh = lane >> 5;
    const int wr = wave >> 2, wc = wave & 3;

    // ds_read byte offsets (slot-relative), per subk s and frag index.
    int offA[2][2], offB[2][2];
    #pragma unroll
    for (int s = 0; s < 2; ++s) {
        #pragma unroll
        for (int mi = 0; mi < 2; ++mi)
            offA[s][mi] = (2 * s + lh) * 2048 + (wr * 64 + mi * 32 + l31) * 16;
        #pragma unroll
        for (int nj = 0; nj < 2; ++nj)
            offB[s][nj] = 8192 + (2 * s + lh) * 4096 + (wc * 64 + nj * 32 + l31) * 16;
    }

    // Staging (linear, no swizzle). Thread t: A chunk c=t (kc=t>>7,row=t&127);
    // B chunks c=t and c=t+512 (kc=c>>8, row=c&255).
    const u16* pA  = A + (size_t)(m0 + (tid & 127)) * lda + (tid >> 7) * 8;
    const u16* pB  = B + (size_t)(n0 + (tid & 255)) * ldb + (tid >> 8) * 8;
    const u16* pB2 = B + (size_t)(n0 + (tid & 255)) * ldb + (2 + (tid >> 8)) * 8;
    const int t8 = tid * 8;

#define STG(s) do {                                        \
        u16* b_ = lds + (s) * 12288;                       \
        gload_lds16(pA,  b_ + t8);                         \
        gload_lds16(pB,  b_ + 4096 + t8);                  \
        gload_lds16(pB2, b_ + 8192 + t8);                  \
        pA += 32; pB += 32; pB2 += 32;                     \
    } while (0)

    // Prologue: stage slots 0,1; drain slot 0 (keep slot 1's 3 in flight).
    STG(0); STG(1);
    asm volatile("s_waitcnt vmcnt(3)" ::: "memory");
    __builtin_amdgcn_s_barrier();
    __builtin_amdgcn_sched_barrier(0);

    int sl = 0;
    for (int i = 0; i < NK; ++i) {
        const char* sb = (const char*)(lds + sl * 12288);
        bf16x8 af[2][2], bv[2][2];
        #pragma unroll
        for (int s = 0; s < 2; ++s) {
            #pragma unroll
            for (int mi = 0; mi < 2; ++mi)
                af[s][mi] = *(const bf16x8*)(sb + offA[s][mi]);
            #pragma unroll
            for (int nj = 0; nj < 2; ++nj)
                bv[s][nj] = *(const bf16x8*)(sb + offB[s][nj]);
        }

        int s2 = sl + 2; if (s2 >= 3) s2 -= 3;
        if (i + 2 < NK) STG(s2);

        __builtin_amdgcn_s_setprio(1);
        #pragma unroll
        for (int s = 0; s < 2; ++s)
            #pragma unroll
            for (int mi = 0; mi < 2; ++mi)
                #pragma unroll
                for (int nj = 0; nj < 2; ++nj)
                    acc[mi][nj] = __builtin_amdgcn_mfma_f32_32x32x16_bf16(
                        af[s][mi], bv[s][nj], acc[mi][nj], 0, 0, 0);
        __builtin_amdgcn_s_setprio(0);

        if (i + 1 < NK) {
            // Drain own loads for slot i+1, THEN barrier (R7-bug ordering fix).
            if (i + 2 < NK) { asm volatile("s_waitcnt vmcnt(3)" ::: "memory"); }
            else            { asm volatile("s_waitcnt vmcnt(0)" ::: "memory"); }
            __builtin_amdgcn_s_barrier();
            __builtin_amdgcn_sched_barrier(0);
        }
        sl = (sl == 2) ? 0 : sl + 1;
    }
#undef STG
}

// Output coords (32x32 C/D): row = m0 + wr*64 + mi*32 + (r&3)+8*(r>>2)+4*lh,
//                            col = n0 + wc*64 + nj*32 + l31
#define EPI_COORDS()                                        \
    const int tid = threadIdx.x;                            \
    const int wave = tid >> 6, lane = tid & 63;             \
    const int l31 = lane & 31, lh = lane >> 5;              \
    const int wr = wave >> 2, wc = wave & 3;                \
    (void)tid;

#define CROW(r) (((r) & 3) + 8 * ((r) >> 2) + 4 * lh)

// ---------------------------------------------------------------------------
// Prep kernels
// ---------------------------------------------------------------------------
__global__ __launch_bounds__(256) void k_cast_x(const float* __restrict__ x, u16* __restrict__ xb)
{
    size_t i = (size_t)blockIdx.x * 256 + threadIdx.x;
    float4 f = ((const float4*)x)[i];
    ushort4 o;
    o.x = f2bf(f.x); o.y = f2bf(f.y); o.z = f2bf(f.z); o.w = f2bf(f.w);
    ((ushort4*)xb)[i] = o;
}

// in: R x C f32 row-major -> out: Cout x R bf16 row-major, zero-fill c >= C.
__global__ void k_transpose_w(const float* __restrict__ in, u16* __restrict__ out, int R, int C)
{
    __shared__ u16 t[32][33];
    int c0 = blockIdx.x * 32, r0 = blockIdx.y * 32;
    int tx = threadIdx.x, ty = threadIdx.y;
    #pragma unroll
    for (int p = 0; p < 4; ++p) {
        int rr = ty + p * 8;
        int c = c0 + tx;
        t[rr][tx] = (c < C) ? f2bf(in[(size_t)(r0 + rr) * C + c]) : (u16)0;
    }
    __syncthreads();
    #pragma unroll
    for (int p = 0; p < 4; ++p) {
        int cc = ty + p * 8;
        out[(size_t)(c0 + cc) * R + r0 + tx] = t[tx][cc];
    }
}

// ---------------------------------------------------------------------------
// GEMM1: h = x@Wi (raw acc, bf16) -> h[16384][3328]. Minimal epilogue.
// Grid: 1664 = 128 m-tiles x 13 n-tiles (m fast: same-XCD blocks share B).
// ---------------------------------------------------------------------------
__global__ __launch_bounds__(512, 4) void k_gemm1(
    const u16* __restrict__ xb, const u16* __restrict__ WibT, u16* __restrict__ h)
{
    __shared__ __align__(16) u16 lds[3 * 12288];
    f32x16 acc[2][2] = {};
    int L = xcd_swz(blockIdx.x, 1664);
    int m0 = (L % 128) * 128, n0 = (L / 128) * 256;
    gemm_core(xb, 768, WibT, 768, 24, m0, n0, lds, acc);

    EPI_COORDS();
    #pragma unroll
    for (int mi = 0; mi < 2; ++mi)
        #pragma unroll
        for (int nj = 0; nj < 2; ++nj)
            #pragma unroll
            for (int r = 0; r < 16; ++r) {
                int m = m0 + wr * 64 + mi * 32 + CROW(r);
                int n = n0 + wc * 64 + nj * 32 + l31;
                h[(size_t)m * 3328 + n] = f2bf(acc[mi][nj][r]);
            }
}

// ---------------------------------------------------------------------------
// Split pass: silu(h+bi) -> u in-place (cols 0..1535), vT (transposed),
// q/k (affine). Memory-bound. Grid (256, 50), 256 thr; 64x64 tile per block.
// ---------------------------------------------------------------------------
typedef __bf16 bf16x8v __attribute__((ext_vector_type(8)));
__global__ __launch_bounds__(256) void k_split(
    u16* __restrict__ h, const float* __restrict__ bi,
    const float* __restrict__ gq, const float* __restrict__ bq,
    const float* __restrict__ gk, const float* __restrict__ bk,
    u16* __restrict__ vT, u16* __restrict__ pq, u16* __restrict__ pk)
{
    const int m0 = blockIdx.x * 64, n0 = blockIdx.y * 64;
    const int tid = threadIdx.x;
    const int rrow = tid >> 2, c0 = (tid & 3) * 16;

    if (n0 < 1536) {                       // u region: in-place silu
        size_t base = (size_t)(m0 + rrow) * 3328 + n0 + c0;
        #pragma unroll
        for (int g = 0; g < 2; ++g) {
            bf16x8v hv = *(const bf16x8v*)(h + base + g * 8);
            u16 ov[8];
            #pragma unroll
            for (int e = 0; e < 8; ++e) {
                float val = (float)hv[e] + bi[n0 + c0 + g * 8 + e];
                ov[e] = f2bf(val / (1.f + __expf(-val)));
            }
            *(uint4*)(h + base + g * 8) = *(const uint4*)ov;
        }
    } else if (n0 < 3072) {                // v region: silu + transpose -> vT
        __shared__ u16 t[64][72];
        size_t base = (size_t)(m0 + rrow) * 3328 + n0 + c0;
        #pragma unroll
        for (int g = 0; g < 2; ++g) {
            bf16x8v hv = *(const bf16x8v*)(h + base + g * 8);
            #pragma unroll
            for (int e = 0; e < 8; ++e) {
                float val = (float)hv[e] + bi[n0 + c0 + g * 8 + e];
                t[rrow][c0 + g * 8 + e] = f2bf(val / (1.f + __expf(-val)));
            }
        }
        __syncthreads();
        const int b = m0 >> 12, mm = m0 & 4095, d0 = n0 - 1536;
        #pragma unroll
        for (int p = 0; p < 2; ++p) {
            int dr = (tid >> 3) + p * 32;
            int nc = (tid & 7) * 8;
            u16 tmp[8];
            #pragma unroll
            for (int e = 0; e < 8; ++e) tmp[e] = t[nc + e][dr];
            *(uint4*)(vT + (size_t)b * 1536 * 4096 + (size_t)(d0 + dr) * 4096 + mm + nc) = *(const uint4*)tmp;
        }
    } else {                               // qk region: silu + affine
        size_t base = (size_t)(m0 + rrow) * 3328 + n0 + c0;
        int cb = n0 + c0 - 3072;
        u16 qv[16], kv[16];
        #pragma unroll
        for (int g = 0; g < 2; ++g) {
            bf16x8v hv = *(const bf16x8v*)(h + base + g * 8);
            #pragma unroll
            for (int e = 0; e < 8; ++e) {
                int c = cb + g * 8 + e;
                float val = (float)hv[e] + bi[3072 + c];
                float s = val / (1.f + __expf(-val));
                qv[g * 8 + e] = f2bf(s * gq[c] + bq[c]);
                kv[g * 8 + e] = f2bf(s * gk[c] + bk[c]);
            }
        }
        size_t ob = (size_t)(m0 + rrow) * 128 + cb;
        *(uint4*)(pq + ob)     = *(const uint4*)qv;
        *(uint4*)(pq + ob + 8) = *(const uint4*)(qv + 8);
        *(uint4*)(pk + ob)     = *(const uint4*)kv;
        *(uint4*)(pk + ob + 8) = *(const uint4*)(kv + 8);
    }
}

// ---------------------------------------------------------------------------
// Scores: P = relu(q@k^T / sqrt(128))^2 / 4096, ONE batch per launch
// (P then stays L3-resident for the immediately following k_zu).
// Grid 512 = 32 m-tiles x 16 n-tiles.
// ---------------------------------------------------------------------------
__global__ __launch_bounds__(512, 4) void k_scores(
    const u16* __restrict__ q, const u16* __restrict__ k, u16* __restrict__ P, int b)
{
    __shared__ __align__(16) u16 lds[3 * 12288];
    f32x16 acc[2][2] = {};
    const u16* A = q + (size_t)b * 4096 * 128;
    const u16* B = k + (size_t)b * 4096 * 128;
    int L = xcd_swz(blockIdx.x, 512);
    int m0 = (L % 32) * 128, n0 = (L / 32) * 256;
    gemm_core(A, 128, B, 128, 4, m0, n0, lds, acc);

    const float sc = 1.f / (128.f * 4096.f);
    EPI_COORDS();
    #pragma unroll
    for (int mi = 0; mi < 2; ++mi)
        #pragma unroll
        for (int nj = 0; nj < 2; ++nj)
            #pragma unroll
            for (int r = 0; r < 16; ++r) {
                int m = m0 + wr * 64 + mi * 32 + CROW(r);
                int n = n0 + wc * 64 + nj * 32 + l31;
                float a = fmaxf(acc[mi][nj][r], 0.f);
                P[(size_t)m * 4096 + n] = f2bf(a * a * sc);
            }
}

// ---------------------------------------------------------------------------
// PV: z = P @ v (B = vT); epilogue uz = u * z in place over h's u-region.
// ONE batch per launch. Grid 192 = 32 m-tiles x 6 n-tiles (m fast).
// ---------------------------------------------------------------------------
__global__ __launch_bounds__(512, 4) void k_zu(
    const u16* __restrict__ P, const u16* __restrict__ vT, u16* __restrict__ h, int b)
{
    __shared__ __align__(16) u16 lds[3 * 12288];
    f32x16 acc[2][2] = {};
    const u16* B = vT + (size_t)b * 1536 * 4096;    // 1536 x 4096 (N x K)
    int L = xcd_swz(blockIdx.x, 192);
    int m0 = (L % 32) * 128, n0 = (L / 32) * 256;
    gemm_core(P, 4096, B, 4096, 128, m0, n0, lds, acc);

    EPI_COORDS();
    #pragma unroll
    for (int mi = 0; mi < 2; ++mi)
        #pragma unroll
        for (int nj = 0; nj < 2; ++nj)
            #pragma unroll
            for (int r = 0; r < 16; ++r) {
                int m = m0 + wr * 64 + mi * 32 + CROW(r);
                int n = n0 + wc * 64 + nj * 32 + l31;
                size_t idx = (size_t)(b * 4096 + m) * 3328 + n;
                h[idx] = f2bf(bf2f(h[idx]) * acc[mi][nj][r]);
            }
}

// ---------------------------------------------------------------------------
// GEMM3: o = (u*z) @ Wo + bo -> f32 out  (A = h's u-region, lda 3328)
// Grid 384 = 128 m-tiles x 3 n-tiles.
// ---------------------------------------------------------------------------
__global__ __launch_bounds__(512, 4) void k_out(
    const u16* __restrict__ h, const u16* __restrict__ WobT,
    const float* __restrict__ bo, float* __restrict__ out)
{
    __shared__ __align__(16) u16 lds[3 * 12288];
    f32x16 acc[2][2] = {};
    int L = xcd_swz(blockIdx.x, 384);
    int m0 = (L % 128) * 128, n0 = (L / 128) * 256;
    gemm_core(h, 3328, WobT, 1536, 48, m0, n0, lds, acc);

    EPI_COORDS();
    #pragma unroll
    for (int mi = 0; mi < 2; ++mi)
        #pragma unroll
        for (int nj = 0; nj < 2; ++nj)
            #pragma unroll
            for (int r = 0; r < 16; ++r) {
                int m = m0 + wr * 64 + mi * 32 + CROW(r);
                int n = n0 + wc * 64 + nj * 32 + l31;
                out[(size_t)m * 768 + n] = acc[mi][nj][r] + bo[n];
            }
}

// ---------------------------------------------------------------------------
extern "C" void kernel_launch(void* const* d_in, const int* in_sizes, int n_in,
                              void* d_out, int out_size, void* d_ws, size_t ws_size,
                              hipStream_t stream)
{
    const float* x  = (const float*)d_in[0];
    const float* Wi = (const float*)d_in[1];
    const float* bi = (const float*)d_in[2];
    const float* gq = (const float*)d_in[3];
    const float* bq = (const float*)d_in[4];
    const float* gk = (const float*)d_in[5];
    const float* bk = (const float*)d_in[6];
    const float* Wo = (const float*)d_in[7];
    const float* bo = (const float*)d_in[8];
    float* out = (float*)d_out;

    char* ws = (char*)d_ws;
    size_t off = 0;
    auto alloc = [&](size_t bytes) -> void* {
        void* p = ws + off;
        off += (bytes + 255) & ~(size_t)255;
        return p;
    };
    u16* xb   = (u16*)alloc((size_t)16384 * 768 * 2);
    u16* WibT = (u16*)alloc((size_t)3328 * 768 * 2);     // padded N: 3200 -> 3328
    u16* WobT = (u16*)alloc((size_t)768 * 1536 * 2);
    u16* h    = (u16*)alloc((size_t)16384 * 3328 * 2);   // raw GEMM1 out; u/uz in place
    u16* vT   = (u16*)alloc((size_t)4 * 1536 * 4096 * 2);
    u16* q    = (u16*)alloc((size_t)16384 * 128 * 2);
    u16* k    = (u16*)alloc((size_t)16384 * 128 * 2);
    u16* P    = (u16*)alloc((size_t)4096 * 4096 * 2);    // 1 batch: L3-resident

    k_cast_x<<<dim3(12288), dim3(256), 0, stream>>>(x, xb);
    k_transpose_w<<<dim3(3328 / 32, 768 / 32), dim3(32, 8), 0, stream>>>(Wi, WibT, 768, 3200);
    k_transpose_w<<<dim3(768 / 32, 1536 / 32), dim3(32, 8), 0, stream>>>(Wo, WobT, 1536, 768);

    k_gemm1<<<dim3(1664), dim3(512), 0, stream>>>(xb, WibT, h);
    k_split<<<dim3(256, 50), dim3(256), 0, stream>>>(h, bi, gq, bq, gk, bk, vT, q, k);

    for (int b = 0; b < 4; ++b) {
        k_scores<<<dim3(512), dim3(512), 0, stream>>>(q, k, P, b);
        k_zu<<<dim3(192), dim3(512), 0, stream>>>(P, vT, h, b);
    }

    k_out<<<dim3(384), dim3(512), 0, stream>>>(h, WobT, bo, out);
}

// Round 10
// 529.921 us; speedup vs baseline: 1.6939x; 1.6939x over previous
//
#include <hip/hip_runtime.h>
#include <hip/hip_bf16.h>

typedef unsigned short u16;
typedef __bf16 bf16x8 __attribute__((ext_vector_type(8)));
typedef float f32x16 __attribute__((ext_vector_type(16)));

#define DEVI __device__ __forceinline__

DEVI u16 f2bf(float f) {
    unsigned u = __builtin_bit_cast(unsigned, f);
    u += 0x7fff + ((u >> 16) & 1);   // RNE; inputs are finite
    return (u16)(u >> 16);
}
DEVI float bf2f(u16 h) {
    unsigned u = ((unsigned)h) << 16;
    return __builtin_bit_cast(float, u);
}

typedef __attribute__((address_space(1))) const unsigned GU32;
typedef __attribute__((address_space(3))) unsigned LU32;

DEVI void gload_lds16(const void* g, void* l) {
    __builtin_amdgcn_global_load_lds((GU32*)g, (LU32*)l, 16, 0, 0);
}

// Bijective XCD-chunk swizzle (m204).
DEVI int xcd_swz(int orig, int n) {
    int q = n >> 3, r = n & 7, x = orig & 7, o = orig >> 3;
    return (x < r ? x * (q + 1) : r * (q + 1) + (x - r) * q) + o;
}

// ===========================================================================
// 128x256 GEMM core: mfma_f32_32x32x16_bf16 on the R8-proven LDS scheme.
//   C[128x256] += A[MxK] * B^T  (B stored N x K row-major)
//   512 thr = 8 waves (2M x 4N); wave tile 64x64 = 2x2 frags of 32x32.
//   LDS slot 24KB: A [128 rows][64B] + B [256 rows][64B] @+8192B; ring-3.
//   STAGING (R8, coalesced): thread t covers row t>>2, 16B chunk (t&3),
//   source column inverse-XOR-swizzled; LDS dest linear (gload_lds req).
//   FRAG READS (32x32): lane reads 16B at row=base+l31,
//   col=(s*32+lh*16)^(((row>>1)&3)<<4) -> swizzle spreads 32 lanes over
//   16 banks = 2-way aliasing = free (m136).
//   A/B frag: row/col=lane&31, k=s*16+(lane>>5)*8+e (verified R9, absmax ok).
//   C/D: col=lane&31, row=(r&3)+8*(r>>2)+4*(lane>>5)  (m74/m101, verified).
//   Schedule = R8 (passing): per iter {ds_read slot i%3; stage slot (i+2)%3;
//   8 MFMA setprio; vmcnt(3) drain own loads for slot i+1; s_barrier}.
// ===========================================================================
DEVI void gemm_core(const u16* __restrict__ A, int lda,
                    const u16* __restrict__ B, int ldb,
                    int NK, int m0, int n0, u16* lds, f32x16 (&acc)[2][2])
{
    const int tid = threadIdx.x;
    const int wave = tid >> 6, lane = tid & 63;
    const int l31 = lane & 31, lh = lane >> 5;
    const int wr = wave >> 2, wc = wave & 3;

    // Swizzled ds_read byte offsets (slot-relative), per subk s, frag idx.
    int offA[2][2], offB[2][2];
    #pragma unroll
    for (int s = 0; s < 2; ++s) {
        #pragma unroll
        for (int mi = 0; mi < 2; ++mi) {
            int ra = wr * 64 + mi * 32 + l31;
            offA[s][mi] = ra * 64 + ((s * 32 + lh * 16) ^ (((ra >> 1) & 3) << 4));
        }
        #pragma unroll
        for (int nj = 0; nj < 2; ++nj) {
            int rb = wc * 64 + nj * 32 + l31;
            offB[s][nj] = 8192 + rb * 64 + ((s * 32 + lh * 16) ^ (((rb >> 1) & 3) << 4));
        }
    }

    // Staging (R8): thread t -> row t>>2 (A and B rows 0..127) and row
    // 128+(t>>2) (B rows 128..255), 16B chunk (t&3), src col inverse-swizzled
    // ((r>>1)&3 == (t>>3)&3, invariant under r+=128).
    const int rs = tid >> 2;
    const int cl = (tid & 3) ^ ((tid >> 3) & 3);
    const u16* pA  = A + (size_t)(m0 + rs) * lda + cl * 8;
    const u16* pB  = B + (size_t)(n0 + rs) * ldb + cl * 8;
    const u16* pB2 = pB + (size_t)128 * ldb;
    const int t8 = tid * 8;

#define STG(s) do {                                        \
        u16* b_ = lds + (s) * 12288;                       \
        gload_lds16(pA,  b_ + t8);                         \
        gload_lds16(pB,  b_ + 4096 + t8);                  \
        gload_lds16(pB2, b_ + 8192 + t8);                  \
        pA += 32; pB += 32; pB2 += 32;                     \
    } while (0)

    // Prologue: stage slots 0,1; drain slot 0 (keep slot 1's 3 in flight).
    STG(0); STG(1);
    asm volatile("s_waitcnt vmcnt(3)" ::: "memory");
    __builtin_amdgcn_s_barrier();
    __builtin_amdgcn_sched_barrier(0);

    int sl = 0;
    for (int i = 0; i < NK; ++i) {
        const char* sb = (const char*)(lds + sl * 12288);
        bf16x8 af[2][2], bv[2][2];
        #pragma unroll
        for (int s = 0; s < 2; ++s) {
            #pragma unroll
            for (int mi = 0; mi < 2; ++mi)
                af[s][mi] = *(const bf16x8*)(sb + offA[s][mi]);
            #pragma unroll
            for (int nj = 0; nj < 2; ++nj)
                bv[s][nj] = *(const bf16x8*)(sb + offB[s][nj]);
        }

        int s2 = sl + 2; if (s2 >= 3) s2 -= 3;
        if (i + 2 < NK) STG(s2);

        __builtin_amdgcn_s_setprio(1);
        #pragma unroll
        for (int s = 0; s < 2; ++s)
            #pragma unroll
            for (int mi = 0; mi < 2; ++mi)
                #pragma unroll
                for (int nj = 0; nj < 2; ++nj)
                    acc[mi][nj] = __builtin_amdgcn_mfma_f32_32x32x16_bf16(
                        af[s][mi], bv[s][nj], acc[mi][nj], 0, 0, 0);
        __builtin_amdgcn_s_setprio(0);

        if (i + 1 < NK) {
            // Drain own loads for slot i+1, THEN barrier (R7-bug ordering).
            if (i + 2 < NK) { asm volatile("s_waitcnt vmcnt(3)" ::: "memory"); }
            else            { asm volatile("s_waitcnt vmcnt(0)" ::: "memory"); }
            __builtin_amdgcn_s_barrier();
            __builtin_amdgcn_sched_barrier(0);
        }
        sl = (sl == 2) ? 0 : sl + 1;
    }
#undef STG
}

// Output coords (32x32 C/D): row = m0 + wr*64 + mi*32 + (r&3)+8*(r>>2)+4*lh,
//                            col = n0 + wc*64 + nj*32 + l31
#define EPI_COORDS()                                        \
    const int tid = threadIdx.x;                            \
    const int wave = tid >> 6, lane = tid & 63;             \
    const int l31 = lane & 31, lh = lane >> 5;              \
    const int wr = wave >> 2, wc = wave & 3;                \
    (void)tid;

#define CROW(r) (((r) & 3) + 8 * ((r) >> 2) + 4 * lh)

// ---------------------------------------------------------------------------
// Prep kernels
// ---------------------------------------------------------------------------
__global__ __launch_bounds__(256) void k_cast_x(const float* __restrict__ x, u16* __restrict__ xb)
{
    size_t i = (size_t)blockIdx.x * 256 + threadIdx.x;
    float4 f = ((const float4*)x)[i];
    ushort4 o;
    o.x = f2bf(f.x); o.y = f2bf(f.y); o.z = f2bf(f.z); o.w = f2bf(f.w);
    ((ushort4*)xb)[i] = o;
}

// in: R x C f32 row-major -> out: Cout x R bf16 row-major, zero-fill c >= C.
__global__ void k_transpose_w(const float* __restrict__ in, u16* __restrict__ out, int R, int C)
{
    __shared__ u16 t[32][33];
    int c0 = blockIdx.x * 32, r0 = blockIdx.y * 32;
    int tx = threadIdx.x, ty = threadIdx.y;
    #pragma unroll
    for (int p = 0; p < 4; ++p) {
        int rr = ty + p * 8;
        int c = c0 + tx;
        t[rr][tx] = (c < C) ? f2bf(in[(size_t)(r0 + rr) * C + c]) : (u16)0;
    }
    __syncthreads();
    #pragma unroll
    for (int p = 0; p < 4; ++p) {
        int cc = ty + p * 8;
        out[(size_t)(c0 + cc) * R + r0 + tx] = t[tx][cc];
    }
}

// ---------------------------------------------------------------------------
// GEMM1: h = x@Wi (raw acc, bf16) -> h[16384][3328]. Minimal epilogue.
// Grid: 1664 = 128 m-tiles x 13 n-tiles (m fast: same-XCD blocks share B).
// ---------------------------------------------------------------------------
__global__ __launch_bounds__(512, 4) void k_gemm1(
    const u16* __restrict__ xb, const u16* __restrict__ WibT, u16* __restrict__ h)
{
    __shared__ __align__(16) u16 lds[3 * 12288];
    f32x16 acc[2][2] = {};
    int L = xcd_swz(blockIdx.x, 1664);
    int m0 = (L % 128) * 128, n0 = (L / 128) * 256;
    gemm_core(xb, 768, WibT, 768, 24, m0, n0, lds, acc);

    EPI_COORDS();
    #pragma unroll
    for (int mi = 0; mi < 2; ++mi)
        #pragma unroll
        for (int nj = 0; nj < 2; ++nj)
            #pragma unroll
            for (int r = 0; r < 16; ++r) {
                int m = m0 + wr * 64 + mi * 32 + CROW(r);
                int n = n0 + wc * 64 + nj * 32 + l31;
                h[(size_t)m * 3328 + n] = f2bf(acc[mi][nj][r]);
            }
}

// ---------------------------------------------------------------------------
// Split pass: silu(h+bi) -> u in-place (cols 0..1535), vT (transposed),
// q/k (affine). Memory-bound. Grid (256, 50), 256 thr; 64x64 tile per block.
// ---------------------------------------------------------------------------
__global__ __launch_bounds__(256) void k_split(
    u16* __restrict__ h, const float* __restrict__ bi,
    const float* __restrict__ gq, const float* __restrict__ bq,
    const float* __restrict__ gk, const float* __restrict__ bk,
    u16* __restrict__ vT, u16* __restrict__ pq, u16* __restrict__ pk)
{
    const int m0 = blockIdx.x * 64, n0 = blockIdx.y * 64;
    const int tid = threadIdx.x;
    const int rrow = tid >> 2, c0 = (tid & 3) * 16;

    if (n0 < 1536) {                       // u region: in-place silu
        size_t base = (size_t)(m0 + rrow) * 3328 + n0 + c0;
        #pragma unroll
        for (int g = 0; g < 2; ++g) {
            bf16x8 hv = *(const bf16x8*)(h + base + g * 8);
            u16 ov[8];
            #pragma unroll
            for (int e = 0; e < 8; ++e) {
                float val = (float)hv[e] + bi[n0 + c0 + g * 8 + e];
                ov[e] = f2bf(val / (1.f + __expf(-val)));
            }
            *(uint4*)(h + base + g * 8) = *(const uint4*)ov;
        }
    } else if (n0 < 3072) {                // v region: silu + transpose -> vT
        __shared__ u16 t[64][72];
        size_t base = (size_t)(m0 + rrow) * 3328 + n0 + c0;
        #pragma unroll
        for (int g = 0; g < 2; ++g) {
            bf16x8 hv = *(const bf16x8*)(h + base + g * 8);
            #pragma unroll
            for (int e = 0; e < 8; ++e) {
                float val = (float)hv[e] + bi[n0 + c0 + g * 8 + e];
                t[rrow][c0 + g * 8 + e] = f2bf(val / (1.f + __expf(-val)));
            }
        }
        __syncthreads();
        const int b = m0 >> 12, mm = m0 & 4095, d0 = n0 - 1536;
        #pragma unroll
        for (int p = 0; p < 2; ++p) {
            int dr = (tid >> 3) + p * 32;
            int nc = (tid & 7) * 8;
            u16 tmp[8];
            #pragma unroll
            for (int e = 0; e < 8; ++e) tmp[e] = t[nc + e][dr];
            *(uint4*)(vT + (size_t)b * 1536 * 4096 + (size_t)(d0 + dr) * 4096 + mm + nc) = *(const uint4*)tmp;
        }
    } else {                               // qk region: silu + affine
        size_t base = (size_t)(m0 + rrow) * 3328 + n0 + c0;
        int cb = n0 + c0 - 3072;
        u16 qv[16], kv[16];
        #pragma unroll
        for (int g = 0; g < 2; ++g) {
            bf16x8 hv = *(const bf16x8*)(h + base + g * 8);
            #pragma unroll
            for (int e = 0; e < 8; ++e) {
                int c = cb + g * 8 + e;
                float val = (float)hv[e] + bi[3072 + c];
                float s = val / (1.f + __expf(-val));
                qv[g * 8 + e] = f2bf(s * gq[c] + bq[c]);
                kv[g * 8 + e] = f2bf(s * gk[c] + bk[c]);
            }
        }
        size_t ob = (size_t)(m0 + rrow) * 128 + cb;
        *(uint4*)(pq + ob)     = *(const uint4*)qv;
        *(uint4*)(pq + ob + 8) = *(const uint4*)(qv + 8);
        *(uint4*)(pk + ob)     = *(const uint4*)kv;
        *(uint4*)(pk + ob + 8) = *(const uint4*)(kv + 8);
    }
}

// ---------------------------------------------------------------------------
// Scores: P = relu(q@k^T / sqrt(128))^2 / 4096, ONE batch per launch
// (P stays L3-resident for the immediately following k_zu).
// Grid 512 = 32 m-tiles x 16 n-tiles.
// ---------------------------------------------------------------------------
__global__ __launch_bounds__(512, 4) void k_scores(
    const u16* __restrict__ q, const u16* __restrict__ k, u16* __restrict__ P, int b)
{
    __shared__ __align__(16) u16 lds[3 * 12288];
    f32x16 acc[2][2] = {};
    const u16* A = q + (size_t)b * 4096 * 128;
    const u16* B = k + (size_t)b * 4096 * 128;
    int L = xcd_swz(blockIdx.x, 512);
    int m0 = (L % 32) * 128, n0 = (L / 32) * 256;
    gemm_core(A, 128, B, 128, 4, m0, n0, lds, acc);

    const float sc = 1.f / (128.f * 4096.f);
    EPI_COORDS();
    #pragma unroll
    for (int mi = 0; mi < 2; ++mi)
        #pragma unroll
        for (int nj = 0; nj < 2; ++nj)
            #pragma unroll
            for (int r = 0; r < 16; ++r) {
                int m = m0 + wr * 64 + mi * 32 + CROW(r);
                int n = n0 + wc * 64 + nj * 32 + l31;
                float a = fmaxf(acc[mi][nj][r], 0.f);
                P[(size_t)m * 4096 + n] = f2bf(a * a * sc);
            }
}

// ---------------------------------------------------------------------------
// PV: z = P @ v (B = vT); epilogue uz = u * z in place over h's u-region.
// ONE batch per launch. Grid 192 = 32 m-tiles x 6 n-tiles (m fast).
// ---------------------------------------------------------------------------
__global__ __launch_bounds__(512, 4) void k_zu(
    const u16* __restrict__ P, const u16* __restrict__ vT, u16* __restrict__ h, int b)
{
    __shared__ __align__(16) u16 lds[3 * 12288];
    f32x16 acc[2][2] = {};
    const u16* B = vT + (size_t)b * 1536 * 4096;    // 1536 x 4096 (N x K)
    int L = xcd_swz(blockIdx.x, 192);
    int m0 = (L % 32) * 128, n0 = (L / 32) * 256;
    gemm_core(P, 4096, B, 4096, 128, m0, n0, lds, acc);

    EPI_COORDS();
    #pragma unroll
    for (int mi = 0; mi < 2; ++mi)
        #pragma unroll
        for (int nj = 0; nj < 2; ++nj)
            #pragma unroll
            for (int r = 0; r < 16; ++r) {
                int m = m0 + wr * 64 + mi * 32 + CROW(r);
                int n = n0 + wc * 64 + nj * 32 + l31;
                size_t idx = (size_t)(b * 4096 + m) * 3328 + n;
                h[idx] = f2bf(bf2f(h[idx]) * acc[mi][nj][r]);
            }
}

// ---------------------------------------------------------------------------
// GEMM3: o = (u*z) @ Wo + bo -> f32 out  (A = h's u-region, lda 3328)
// Grid 384 = 128 m-tiles x 3 n-tiles.
// ---------------------------------------------------------------------------
__global__ __launch_bounds__(512, 4) void k_out(
    const u16* __restrict__ h, const u16* __restrict__ WobT,
    const float* __restrict__ bo, float* __restrict__ out)
{
    __shared__ __align__(16) u16 lds[3 * 12288];
    f32x16 acc[2][2] = {};
    int L = xcd_swz(blockIdx.x, 384);
    int m0 = (L % 128) * 128, n0 = (L / 128) * 256;
    gemm_core(h, 3328, WobT, 1536, 48, m0, n0, lds, acc);

    EPI_COORDS();
    #pragma unroll
    for (int mi = 0; mi < 2; ++mi)
        #pragma unroll
        for (int nj = 0; nj < 2; ++nj)
            #pragma unroll
            for (int r = 0; r < 16; ++r) {
                int m = m0 + wr * 64 + mi * 32 + CROW(r);
                int n = n0 + wc * 64 + nj * 32 + l31;
                out[(size_t)m * 768 + n] = acc[mi][nj][r] + bo[n];
            }
}

// ---------------------------------------------------------------------------
extern "C" void kernel_launch(void* const* d_in, const int* in_sizes, int n_in,
                              void* d_out, int out_size, void* d_ws, size_t ws_size,
                              hipStream_t stream)
{
    const float* x  = (const float*)d_in[0];
    const float* Wi = (const float*)d_in[1];
    const float* bi = (const float*)d_in[2];
    const float* gq = (const float*)d_in[3];
    const float* bq = (const float*)d_in[4];
    const float* gk = (const float*)d_in[5];
    const float* bk = (const float*)d_in[6];
    const float* Wo = (const float*)d_in[7];
    const float* bo = (const float*)d_in[8];
    float* out = (float*)d_out;

    char* ws = (char*)d_ws;
    size_t off = 0;
    auto alloc = [&](size_t bytes) -> void* {
        void* p = ws + off;
        off += (bytes + 255) & ~(size_t)255;
        return p;
    };
    u16* xb   = (u16*)alloc((size_t)16384 * 768 * 2);
    u16* WibT = (u16*)alloc((size_t)3328 * 768 * 2);     // padded N: 3200 -> 3328
    u16* WobT = (u16*)alloc((size_t)768 * 1536 * 2);
    u16* h    = (u16*)alloc((size_t)16384 * 3328 * 2);   // raw GEMM1 out; u/uz in place
    u16* vT   = (u16*)alloc((size_t)4 * 1536 * 4096 * 2);
    u16* q    = (u16*)alloc((size_t)16384 * 128 * 2);
    u16* k    = (u16*)alloc((size_t)16384 * 128 * 2);
    u16* P    = (u16*)alloc((size_t)4096 * 4096 * 2);    // 1 batch: L3-resident

    k_cast_x<<<dim3(12288), dim3(256), 0, stream>>>(x, xb);
    k_transpose_w<<<dim3(3328 / 32, 768 / 32), dim3(32, 8), 0, stream>>>(Wi, WibT, 768, 3200);
    k_transpose_w<<<dim3(768 / 32, 1536 / 32), dim3(32, 8), 0, stream>>>(Wo, WobT, 1536, 768);

    k_gemm1<<<dim3(1664), dim3(512), 0, stream>>>(xb, WibT, h);
    k_split<<<dim3(256, 50), dim3(256), 0, stream>>>(h, bi, gq, bq, gk, bk, vT, q, k);

    for (int b = 0; b < 4; ++b) {
        k_scores<<<dim3(512), dim3(512), 0, stream>>>(q, k, P, b);
        k_zu<<<dim3(192), dim3(512), 0, stream>>>(P, vT, h, b);
    }

    k_out<<<dim3(384), dim3(512), 0, stream>>>(h, WobT, bo, out);
}